// Round 3
// baseline (565.420 us; speedup 1.0000x reference)
//
#include <hip/hip_runtime.h>

typedef __bf16 bf16x8 __attribute__((ext_vector_type(8)));
typedef float  f32x4  __attribute__((ext_vector_type(4)));

__device__ __forceinline__ unsigned short f2bf(float x){
  unsigned int u = __float_as_uint(x);
  u += 0x7fffu + ((u >> 16) & 1u);          // RNE
  return (unsigned short)(u >> 16);
}
__device__ __forceinline__ float sigm(float x){
  return __builtin_amdgcn_rcpf(1.0f + __builtin_amdgcn_exp2f(-1.44269504f * x));
}
__device__ __forceinline__ float tanh_(float x){
  return fmaf(-2.0f, __builtin_amdgcn_rcpf(1.0f + __builtin_amdgcn_exp2f(2.88539008f * x)), 1.0f);
}

// ---------------------------------------------------------------------------
// Weight pack: MFMA B-fragment order (bf16), lane holds B[k=kt*32+(lane>>4)*8+jj][n=lane&15].
// Frag sections:
//   [0,48)    encL0 (ntile*3+kt)  K: [x 0..16 | pad | h 32..96]
//   [48,112)  encL1 (ntile*4+kt)  K: [h0 0..64 | h1 64..128]
//   [112,192) decL0 (ntile*5+kt)  K: [q 0..16 | pad | h1 32..96 | h2 96..160 (Wg)]
//             Wg = dWih0 @ W_in @ Wout   (fused feedback path)
//   [192,256) decL1 (ntile*4+kt)
//   [256,258) W_out (N=4 padded to 16, K=64)
// ---------------------------------------------------------------------------
__global__ void pack_weights(const float* __restrict__ eWih0, const float* __restrict__ eWhh0,
                             const float* __restrict__ eWih1, const float* __restrict__ eWhh1,
                             const float* __restrict__ dWih0, const float* __restrict__ dWhh0,
                             const float* __restrict__ dWih1, const float* __restrict__ dWhh1,
                             const float* __restrict__ W_in,  const float* __restrict__ Wout,
                             unsigned short* __restrict__ out){
  int t = blockIdx.x * 256 + threadIdx.x;
  if (t >= 258 * 64) return;
  int lane = t & 63;
  int f    = t >> 6;
  unsigned short vals[8];
  if (f >= 256){                                       // W_out frags
    int kt = f - 256, n = lane & 15;
#pragma unroll
    for (int jj = 0; jj < 8; jj++){
      int k = kt * 32 + (lane >> 4) * 8 + jj;
      vals[jj] = (n < 4) ? f2bf(Wout[n * 64 + k]) : (unsigned short)0;
    }
  } else if (f >= 112 && f < 192 && ((f - 112) % 5) >= 3){   // decL0 Wg k-tiles
    int ntile = (f - 112) / 5, kt = (f - 112) % 5;
    int n = ntile * 16 + (lane & 15);
#pragma unroll
    for (int jj = 0; jj < 8; jj++){
      int k2 = (kt - 3) * 32 + (lane >> 4) * 8 + jj;   // h2 index 0..64
      float s = 0.0f;
#pragma unroll
      for (int m = 0; m < 16; m++){
        float wf = 0.0f;
#pragma unroll
        for (int i = 0; i < 4; i++) wf = fmaf(W_in[m * 4 + i], Wout[i * 64 + k2], wf);
        s = fmaf(dWih0[n * 16 + m], wf, s);
      }
      vals[jj] = f2bf(s);
    }
  } else {
    const float *Wih, *Whh; int kx, ntile, kt;
    if (f < 48)       { Wih=eWih0; Whh=eWhh0; kx=16; ntile=f/3;        kt=f%3; }
    else if (f < 112) { Wih=eWih1; Whh=eWhh1; kx=64; ntile=(f-48)/4;   kt=(f-48)%4; }
    else if (f < 192) { Wih=dWih0; Whh=dWhh0; kx=16; ntile=(f-112)/5;  kt=(f-112)%5; }
    else              { Wih=dWih1; Whh=dWhh1; kx=64; ntile=(f-192)/4;  kt=(f-192)%4; }
    int n    = ntile * 16 + (lane & 15);
    int hoff = (kx == 16) ? 32 : 64;
#pragma unroll
    for (int jj = 0; jj < 8; jj++){
      int k = kt * 32 + (lane >> 4) * 8 + jj;
      float v;
      if (k < kx)        v = Wih[n * kx + k];
      else if (k < hoff) v = 0.0f;
      else               v = Whh[n * 64 + (k - hoff)];
      vals[jj] = f2bf(v);
    }
  }
  uint4 o;
  o.x = (unsigned)vals[0] | ((unsigned)vals[1] << 16);
  o.y = (unsigned)vals[2] | ((unsigned)vals[3] << 16);
  o.z = (unsigned)vals[4] | ((unsigned)vals[5] << 16);
  o.w = (unsigned)vals[6] | ((unsigned)vals[7] << 16);
  ((uint4*)out)[f * 64 + lane] = o;
}

// A-layout (per 16-row subtile): elem(m,k) at ((k>>5)*64 + (m | (((k>>3)&3)<<4)))*8 + (k&7)
__device__ __forceinline__ void write_h(unsigned short* buf, int k, int quad,
                                        const unsigned short* h){
  unsigned short* p = buf + (((k >> 5) * 64) + quad * 4 + (((k >> 3) & 3) << 4)) * 8 + (k & 7);
#pragma unroll
  for (int e = 0; e < 4; e++) p[e * 8] = h[e];
}

template<int KT0>
__device__ __forceinline__ void load_frags(const unsigned short* __restrict__ pw,
                                           int base0, int base1, int w, int lane,
                                           bf16x8 (*B0)[4], bf16x8 (*B1)[4]){
#pragma unroll
  for (int g = 0; g < 4; g++){
    int nt = 4 * g + w;
#pragma unroll
    for (int kt = 0; kt < KT0; kt++)
      B0[kt][g] = *(const bf16x8*)(pw + (((long)(base0 + nt * KT0 + kt)) * 64 + lane) * 8);
#pragma unroll
    for (int kt = 0; kt < 4; kt++)
      B1[kt][g] = *(const bf16x8*)(pw + (((long)(base1 + nt * 4 + kt)) * 64 + lane) * 8);
  }
}

// One LSTM cell step for 32 rows (2 row-subtiles of 16), this wave's 16 j's.
template<int KT, int SZ>
__device__ __forceinline__ void cell_compute(const unsigned short* __restrict__ A,
                                             const bf16x8 (*B)[4],
                                             const float* bias,
                                             float* c,
                                             unsigned short* hout,
                                             int lane){
  f32x4 acc[4][2];
#pragma unroll
  for (int g = 0; g < 4; g++){
    f32x4 b = {bias[g], bias[g], bias[g], bias[g]};
    acc[g][0] = b; acc[g][1] = b;
  }
#pragma unroll
  for (int kt = 0; kt < KT; kt++){
    bf16x8 a0 = *(const bf16x8*)(A +      (kt * 64 + lane) * 8);
    bf16x8 a1 = *(const bf16x8*)(A + SZ + (kt * 64 + lane) * 8);
#pragma unroll
    for (int g = 0; g < 4; g++){
      acc[g][0] = __builtin_amdgcn_mfma_f32_16x16x32_bf16(a0, B[kt][g], acc[g][0], 0, 0, 0);
      acc[g][1] = __builtin_amdgcn_mfma_f32_16x16x32_bf16(a1, B[kt][g], acc[g][1], 0, 0, 0);
    }
  }
#pragma unroll
  for (int rt = 0; rt < 2; rt++){
#pragma unroll
    for (int e = 0; e < 4; e++){
      float is = sigm(acc[0][rt][e]);
      float fs = sigm(acc[1][rt][e]);
      float gt = tanh_(acc[2][rt][e]);
      float os = sigm(acc[3][rt][e]);
      int idx = rt * 4 + e;
      c[idx] = fmaf(fs, c[idx], is * gt);
      hout[idx] = f2bf(os * tanh_(c[idx]));
    }
  }
}

// ---------------------------------------------------------------------------
// Main: one block = 32 batch rows. Encoder: 1 barrier/step (layer-skewed).
// Decoder: 2 barriers/step (feedback folded into cell0 via Wg; out-proj off
// critical path). 4 waves; wave w owns j-slice [16w,16w+16) for all 4 gates.
// ---------------------------------------------------------------------------
__global__ __launch_bounds__(256, 2)
void lstm_main(const float* __restrict__ src, const float* __restrict__ trg,
               const float* __restrict__ W_in, const float* __restrict__ b_in,
               const float* __restrict__ eb0, const float* __restrict__ eb1,
               const float* __restrict__ db0, const float* __restrict__ db1,
               const float* __restrict__ bout,
               const unsigned short* __restrict__ pw,
               float* __restrict__ out){
  __shared__ __align__(16) unsigned short A0[2][2][2560];   // ping-pong, 2 subtiles, K=160
  __shared__ __align__(16) unsigned short A1[2][2][2048];   // K=128
  __shared__ __align__(16) float xsrc[2][128];              // encoder x ping-pong
  __shared__ __align__(16) unsigned short sWoutF[1024];     // W_out B-frags

  const int tid  = threadIdx.x;
  const int lane = tid & 63;
  const int w    = tid >> 6;
  const int quad = lane >> 4;
  const int l16  = lane & 15;
  const int j    = 16 * w + l16;
  const int rowg0 = blockIdx.x * 32;
  const int mm   = tid & 15;                  // x/q-proj: this thread's m-unit
  const int xr   = tid >> 4;                  // x/q-proj: rows xr and xr+16

  // ---- staging ----
  {
    uint4 z; z.x = z.y = z.z = z.w = 0u;
    uint4* a0p = (uint4*)A0;                  // 1280 uint4
    uint4* a1p = (uint4*)A1;                  // 1024 uint4
    for (int i = tid; i < 1280; i += 256) a0p[i] = z;
    for (int i = tid; i < 1024; i += 256) a1p[i] = z;
    if (tid < 128) ((uint4*)sWoutF)[tid] = ((const uint4*)pw)[256 * 64 + tid];
    if (tid < 128) xsrc[0][tid] = src[(long)(rowg0 + (tid >> 2)) * 256 + (tid & 3)];
  }
  const float4 wv = *(const float4*)&W_in[mm * 4];
  const float  bin = b_in[mm];

  bf16x8 B0[5][4], B1[4][4];
  float bias0[4], bias1[4];
  float c0[8] = {0,0,0,0,0,0,0,0}, c1[8] = {0,0,0,0,0,0,0,0};
  load_frags<3>(pw, 0, 48, w, lane, B0, B1);
#pragma unroll
  for (int g = 0; g < 4; g++){ int n = 64*g + j; bias0[g] = eb0[n]; bias1[g] = eb1[n]; }
  __syncthreads();

  unsigned short h0r[8], h1r[8];
  const int xoff = (xr | ((mm >> 3) << 4)) * 8 + (mm & 7);   // A-layout slot for k=mm

  // ================= encoder: 1 barrier/step (cell1 skewed by 1) =================
  for (int t = 0; t < 64; t++){
    int cur = t & 1, nxt = cur ^ 1;
    float xv;
    if (tid < 128)
      xv = src[(long)(rowg0 + (tid >> 2)) * 256 + ((t == 63 ? 63 : t + 1) << 2) + (tid & 3)];
    { // x-projection for rows xr, xr+16
      float4 x0 = *(const float4*)&xsrc[cur][xr * 4];
      float4 x1 = *(const float4*)&xsrc[cur][(xr + 16) * 4];
      float m0 = bin + x0.x*wv.x + x0.y*wv.y + x0.z*wv.z + x0.w*wv.w;
      float m1 = bin + x1.x*wv.x + x1.y*wv.y + x1.z*wv.z + x1.w*wv.w;
      A0[cur][0][xoff] = f2bf(m0);
      A0[cur][1][xoff] = f2bf(m1);
    }
    if (tid < 128) xsrc[nxt][tid] = xv;
    __syncthreads();
    // cell0(t)
    cell_compute<3, 2560>(&A0[cur][0][0], B0, bias0, c0, h0r, lane);
#pragma unroll
    for (int rt = 0; rt < 2; rt++){
      write_h(&A0[nxt][rt][0], 32 + j, quad, h0r + rt * 4);   // recurrent h0
      write_h(&A1[cur][rt][0],      j, quad, h0r + rt * 4);   // feed layer 1
    }
    // cell1(t-1) — inputs written during iter t-1, visible since barrier above
    if (t > 0){
      cell_compute<4, 2048>(&A1[nxt][0][0], B1, bias1, c1, h1r, lane);
#pragma unroll
      for (int rt = 0; rt < 2; rt++)
        write_h(&A1[cur][rt][0], 64 + j, quad, h1r + rt * 4); // recurrent h1
    }
  }
  __syncthreads();
  // flush cell1(63): h2_enc(63) -> A1[0] recurrent + A0[0] h2-region (decoder t=0)
  cell_compute<4, 2048>(&A1[1][0][0], B1, bias1, c1, h1r, lane);
#pragma unroll
  for (int rt = 0; rt < 2; rt++){
    write_h(&A1[0][rt][0], 64 + j, quad, h1r + rt * 4);
    write_h(&A0[0][rt][0], 96 + j, quad, h1r + rt * 4);
  }

  // ================= decoder =================
  load_frags<5>(pw, 112, 192, w, lane, B0, B1);
#pragma unroll
  for (int g = 0; g < 4; g++){ int n = 64*g + j; bias0[g] = db0[n]; bias1[g] = db1[n]; }
  const float bo = (w < 2 && l16 < 4) ? bout[l16] : 0.0f;
  float bq = bin;                               // b_in + bout @ W_in^T
#pragma unroll
  for (int i = 0; i < 4; i++) bq = fmaf(bout[i], ((const float*)&wv)[i], bq);
  { // A0[0] q-region = m(0) = trg[:,0] @ W_in^T + b_in
    float4 x0 = *(const float4*)&trg[(long)(rowg0 + xr) * 256];
    float4 x1 = *(const float4*)&trg[(long)(rowg0 + xr + 16) * 256];
    float m0 = bin + x0.x*wv.x + x0.y*wv.y + x0.z*wv.z + x0.w*wv.w;
    float m1 = bin + x1.x*wv.x + x1.y*wv.y + x1.z*wv.z + x1.w*wv.w;
    A0[0][0][xoff] = f2bf(m0);
    A0[0][1][xoff] = f2bf(m1);
  }

  for (int t = 0; t < 64; t++){
    int cur = t & 1, nxt = cur ^ 1;
    { // q(t) -> A0[nxt] (recurrence-independent; used by cell0(t+1))
      float4 x0 = *(const float4*)&trg[(long)(rowg0 + xr) * 256 + t * 4];
      float4 x1 = *(const float4*)&trg[(long)(rowg0 + xr + 16) * 256 + t * 4];
      float m0 = bq + x0.x*wv.x + x0.y*wv.y + x0.z*wv.z + x0.w*wv.w;
      float m1 = bq + x1.x*wv.x + x1.y*wv.y + x1.z*wv.z + x1.w*wv.w;
      A0[nxt][0][xoff] = f2bf(m0);
      A0[nxt][1][xoff] = f2bf(m1);
    }
    __syncthreads();                       // barA: q(t-1), h1(t-1), h2(t-1) visible
    cell_compute<5, 2560>(&A0[cur][0][0], B0, bias0, c0, h0r, lane);
#pragma unroll
    for (int rt = 0; rt < 2; rt++){
      write_h(&A0[nxt][rt][0], 32 + j, quad, h0r + rt * 4);   // h1 recurrent
      write_h(&A1[cur][rt][0],      j, quad, h0r + rt * 4);   // feed cell1
    }
    if (w < 2 && t > 0){                   // out-proj(t-1): off critical path
      const unsigned short* Ah = &A0[cur][w][0];
      bf16x8 a3  = *(const bf16x8*)(Ah + (3 * 64 + lane) * 8);
      bf16x8 a4  = *(const bf16x8*)(Ah + (4 * 64 + lane) * 8);
      bf16x8 bw0 = *(const bf16x8*)(sWoutF + lane * 8);
      bf16x8 bw1 = *(const bf16x8*)(sWoutF + 512 + lane * 8);
      f32x4 po = {bo, bo, bo, bo};
      po = __builtin_amdgcn_mfma_f32_16x16x32_bf16(a3, bw0, po, 0, 0, 0);
      po = __builtin_amdgcn_mfma_f32_16x16x32_bf16(a4, bw1, po, 0, 0, 0);
      if (l16 < 4){
#pragma unroll
        for (int e = 0; e < 4; e++){
          int row = w * 16 + quad * 4 + e;
          out[(long)(rowg0 + row) * 256 + (t - 1) * 4 + l16] =
              po[e] + trg[(long)(rowg0 + row) * 256 + (t - 1) * 4 + l16];
        }
      }
    }
    __syncthreads();                       // barB: h0(t) visible
    cell_compute<4, 2048>(&A1[cur][0][0], B1, bias1, c1, h1r, lane);
#pragma unroll
    for (int rt = 0; rt < 2; rt++){
      write_h(&A1[nxt][rt][0], 64 + j, quad, h1r + rt * 4);   // h2 recurrent
      write_h(&A0[nxt][rt][0], 96 + j, quad, h1r + rt * 4);   // h2 -> cell0(t+1)
    }
  }
  __syncthreads();
  // flush out-proj(63): h2(63) sits in A0[0] h2-region (nxt of t=63)
  if (w < 2){
    const unsigned short* Ah = &A0[0][w][0];
    bf16x8 a3  = *(const bf16x8*)(Ah + (3 * 64 + lane) * 8);
    bf16x8 a4  = *(const bf16x8*)(Ah + (4 * 64 + lane) * 8);
    bf16x8 bw0 = *(const bf16x8*)(sWoutF + lane * 8);
    bf16x8 bw1 = *(const bf16x8*)(sWoutF + 512 + lane * 8);
    f32x4 po = {bo, bo, bo, bo};
    po = __builtin_amdgcn_mfma_f32_16x16x32_bf16(a3, bw0, po, 0, 0, 0);
    po = __builtin_amdgcn_mfma_f32_16x16x32_bf16(a4, bw1, po, 0, 0, 0);
    if (l16 < 4){
#pragma unroll
      for (int e = 0; e < 4; e++){
        int row = w * 16 + quad * 4 + e;
        out[(long)(rowg0 + row) * 256 + 63 * 4 + l16] =
            po[e] + trg[(long)(rowg0 + row) * 256 + 63 * 4 + l16];
      }
    }
  }
}

extern "C" void kernel_launch(void* const* d_in, const int* in_sizes, int n_in,
                              void* d_out, int out_size, void* d_ws, size_t ws_size,
                              hipStream_t stream){
  (void)n_in; (void)out_size; (void)ws_size;
  const float* src   = (const float*)d_in[0];
  const float* trg   = (const float*)d_in[1];
  const float* W_in  = (const float*)d_in[2];
  const float* b_in  = (const float*)d_in[3];
  const float* eWih0 = (const float*)d_in[4];
  const float* eWhh0 = (const float*)d_in[5];
  const float* eb0   = (const float*)d_in[6];
  const float* eWih1 = (const float*)d_in[7];
  const float* eWhh1 = (const float*)d_in[8];
  const float* eb1   = (const float*)d_in[9];
  const float* dWih0 = (const float*)d_in[10];
  const float* dWhh0 = (const float*)d_in[11];
  const float* db0   = (const float*)d_in[12];
  const float* dWih1 = (const float*)d_in[13];
  const float* dWhh1 = (const float*)d_in[14];
  const float* db1   = (const float*)d_in[15];
  const float* Wout  = (const float*)d_in[16];
  const float* bout  = (const float*)d_in[17];
  unsigned short* pw = (unsigned short*)d_ws;          // needs 264,192 bytes

  pack_weights<<<65, 256, 0, stream>>>(eWih0, eWhh0, eWih1, eWhh1,
                                       dWih0, dWhh0, dWih1, dWhh1,
                                       W_in, Wout, pw);

  int B    = in_sizes[0] / 256;                        // S*I = 256
  int nblk = B / 32;
  lstm_main<<<nblk, 256, 0, stream>>>(src, trg, W_in, b_in, eb0, eb1, db0, db1,
                                      bout, pw, (float*)d_out);
}